// Round 1
// baseline (178.254 us; speedup 1.0000x reference)
//
#include <hip/hip_runtime.h>
#include <math.h>

#define CHUNK 64
#define MAXNC 64   // supports T up to 4096

// ---------------- K1: q/k/v projections ----------------
// grid (D, B, 3), block 64 (one wave per output scalar)
__global__ void proj_kernel(const float* __restrict__ x,
                            const float* __restrict__ Wq,
                            const float* __restrict__ Wk,
                            const float* __restrict__ Wv,
                            float* __restrict__ qkv, // [3][B][D]
                            int B, int E, int D)
{
    int d = blockIdx.x;
    int b = blockIdx.y;
    int p = blockIdx.z;
    int lane = threadIdx.x; // 0..63
    const float* W = (p == 0) ? Wq : (p == 1) ? Wk : Wv;
    const float* wrow = W + (size_t)d * E;
    const float* xrow = x + (size_t)b * E;
    float acc = 0.f;
    for (int i = 0; i < E; i += 64 * 4) {
        float4 w4 = *(const float4*)(wrow + i + lane * 4);
        float4 x4 = *(const float4*)(xrow + i + lane * 4);
        acc += w4.x * x4.x + w4.y * x4.y + w4.z * x4.z + w4.w * x4.w;
    }
    for (int off = 32; off >= 1; off >>= 1)
        acc += __shfl_xor(acc, off, 64);
    if (lane == 0) qkv[((size_t)p * B + b) * D + d] = acc;
}

// ---------------- K2: scores + per-chunk online-softmax partials ----------------
// grid (NC, B), block 128 (2 waves)
__global__ void score_chunk_kernel(const float* __restrict__ kv,  // [2][B][MT][D]
                                   const float* __restrict__ qkv, // [3][B][D]
                                   const int* __restrict__ next_pos,
                                   float* __restrict__ s_out,     // [B][T]
                                   float* __restrict__ m_out,     // [B][NC]
                                   float* __restrict__ l_out,     // [B][NC]
                                   float* __restrict__ acc_out,   // [B][NC][D]
                                   int B, int D, int T, int MT, int NC, float scale)
{
    int c = blockIdx.x;
    int b = blockIdx.y;
    int tid = threadIdx.x;   // 0..127
    int wave = tid >> 6;
    int lane = tid & 63;

    __shared__ float s_sh[CHUNK];
    __shared__ float w_sh[CHUNK];

    int np = next_pos[b];
    int t0 = c * CHUNK;
    const float* q    = qkv + (size_t)b * D;
    const float* knew = qkv + ((size_t)1 * B + b) * D;
    const float* vnew = qkv + ((size_t)2 * B + b) * D;

    // q fragment held in registers: 2 floats/lane
    float q0 = q[2 * lane];
    float q1 = q[2 * lane + 1];

    const float* kbase = kv + (size_t)b * MT * D;
    // each wave computes 32 rows' dot products
    for (int j = wave * 32; j < wave * 32 + 32; ++j) {
        int t = t0 + j;
        const float* krow = (t == np) ? knew : (kbase + (size_t)t * D);
        float2 k2 = *(const float2*)(krow + 2 * lane);
        float part = q0 * k2.x + q1 * k2.y;
        for (int off = 32; off >= 1; off >>= 1)
            part += __shfl_xor(part, off, 64);
        if (lane == 0) {
            float sv = (t < T) ? part * scale : -1e30f;
            s_sh[j] = sv;
            if (t < T) s_out[(size_t)b * T + t] = sv;
        }
    }
    __syncthreads();

    // wave 0: chunk max, weights, weight-sum
    if (wave == 0) {
        float sv = s_sh[lane];
        float m = sv;
        for (int off = 32; off >= 1; off >>= 1)
            m = fmaxf(m, __shfl_xor(m, off, 64));
        float w = __expf(sv - m);
        w_sh[lane] = w;
        float l = w;
        for (int off = 32; off >= 1; off >>= 1)
            l += __shfl_xor(l, off, 64);
        if (lane == 0) {
            m_out[(size_t)b * NC + c] = m;
            l_out[(size_t)b * NC + c] = l;
        }
    }
    __syncthreads();

    // thread-per-d accumulation of w*v over the chunk
    const float* vbase = kv + ((size_t)B + b) * MT * D;
    float a = 0.f;
    for (int j = 0; j < CHUNK; ++j) {
        int t = t0 + j;
        const float* vrow = (t == np) ? vnew : (vbase + (size_t)t * D);
        a += w_sh[j] * vrow[tid];
    }
    acc_out[((size_t)b * NC + c) * D + tid] = a;
}

// ---------------- K3: carry-in combine + prefix outputs ----------------
// grid (NC, B), block 128 (thread = d)
__global__ void out_kernel(const float* __restrict__ kv,
                           const float* __restrict__ qkv,
                           const int* __restrict__ next_pos,
                           const float* __restrict__ s_in,   // [B][T]
                           const float* __restrict__ m_in,   // [B][NC]
                           const float* __restrict__ l_in,   // [B][NC]
                           const float* __restrict__ acc_in, // [B][NC][D]
                           float* __restrict__ out,          // [B][T][D]
                           int B, int D, int T, int MT, int NC)
{
    int c = blockIdx.x;
    int b = blockIdx.y;
    int tid = threadIdx.x; // 0..127

    __shared__ float ef_sh[MAXNC];
    __shared__ float lef_sh[MAXNC];
    __shared__ float w_sh[CHUNK];
    __shared__ float rl_sh[CHUNK];
    __shared__ float M_sh;

    int np = next_pos[b];
    int t0 = c * CHUNK;

    // M = max over chunks c' <= c (covers the whole prefix of every row here)
    if (tid == 0) {
        float M = -1e30f;
        for (int cc = 0; cc <= c; ++cc)
            M = fmaxf(M, m_in[(size_t)b * NC + cc]);
        M_sh = M;
    }
    __syncthreads();
    float M = M_sh;

    // stage: rescale factors for prior chunks; weights for this chunk's rows
    if (tid < NC) {
        float e = __expf(m_in[(size_t)b * NC + tid] - M);
        ef_sh[tid] = e;
        lef_sh[tid] = l_in[(size_t)b * NC + tid] * e;
    }
    if (tid >= 64) {
        int j = tid - 64;
        int t = t0 + j;
        w_sh[j] = (t < T) ? __expf(s_in[(size_t)b * T + t] - M) : 0.f;
    }
    __syncthreads();

    // threads 0..63: per-row denominators -> reciprocals (parallel divides)
    if (tid < 64) {
        float L = 0.f;
        for (int cc = 0; cc < c; ++cc) L += lef_sh[cc];
        for (int r = 0; r <= tid; ++r) L += w_sh[r];
        rl_sh[tid] = 1.0f / L;
    }

    // all threads: carry-in numerator for this d
    float A = 0.f;
    for (int cc = 0; cc < c; ++cc)
        A += acc_in[((size_t)b * NC + cc) * (size_t)D + tid] * ef_sh[cc];
    __syncthreads();

    // stream v rows, write prefix outputs
    const float* vbase = kv + ((size_t)B + b) * MT * D;
    const float* vnew  = qkv + ((size_t)2 * B + b) * D;
    float* orow = out + ((size_t)b * T + t0) * (size_t)D + tid;
    for (int j = 0; j < CHUNK; ++j) {
        int t = t0 + j;
        if (t >= T) break;
        const float* vrow = (t == np) ? vnew : (vbase + (size_t)t * D);
        A += w_sh[j] * vrow[tid];
        orow[(size_t)j * D] = A * rl_sh[j];
    }
}

extern "C" void kernel_launch(void* const* d_in, const int* in_sizes, int n_in,
                              void* d_out, int out_size, void* d_ws, size_t ws_size,
                              hipStream_t stream) {
    const float* x        = (const float*)d_in[0];
    const float* Wq       = (const float*)d_in[1];
    const float* Wk       = (const float*)d_in[2];
    const float* Wv       = (const float*)d_in[3];
    const float* kv       = (const float*)d_in[4];
    const int*   next_pos = (const int*)d_in[5];
    float* out = (float*)d_out;

    const int B  = in_sizes[5];                 // 32
    const int E  = in_sizes[0] / B;             // 4096
    const int D  = in_sizes[1] / E;             // 128
    const int T  = out_size / (B * D);          // 1536 (fixed: next_pos[0]=MAX_POS-1)
    const int MT = in_sizes[4] / (2 * B * D);   // 2048
    const int NC = (T + CHUNK - 1) / CHUNK;     // 24

    float* ws   = (float*)d_ws;
    float* qkv  = ws;                            // 3*B*D
    float* s    = qkv + (size_t)3 * B * D;       // B*T
    float* m    = s + (size_t)B * T;             // B*NC
    float* l    = m + (size_t)B * NC;            // B*NC
    float* acc  = l + (size_t)B * NC;            // B*NC*D

    const float scale = 1.0f / sqrtf((float)D);

    proj_kernel<<<dim3(D, B, 3), 64, 0, stream>>>(x, Wq, Wk, Wv, qkv, B, E, D);
    score_chunk_kernel<<<dim3(NC, B), 128, 0, stream>>>(kv, qkv, next_pos,
                                                        s, m, l, acc,
                                                        B, D, T, MT, NC, scale);
    out_kernel<<<dim3(NC, B), 128, 0, stream>>>(kv, qkv, next_pos,
                                                s, m, l, acc, out,
                                                B, D, T, MT, NC);
}

// Round 2
// 138.393 us; speedup vs baseline: 1.2880x; 1.2880x over previous
//
#include <hip/hip_runtime.h>
#include <math.h>

#define CHUNK 32   // rows per chunk (NC = ceil(T/32) <= 48 for T=1536)

// ---------------- K1: fused q/k/v projections ----------------
// grid (D, B), block 64. One wave computes q[d],k[d],v[d] for batch b.
__global__ void proj_kernel(const float* __restrict__ x,
                            const float* __restrict__ Wq,
                            const float* __restrict__ Wk,
                            const float* __restrict__ Wv,
                            float* __restrict__ qkv, // [3][B][D]
                            int B, int E, int D)
{
    int d = blockIdx.x;
    int b = blockIdx.y;
    int lane = threadIdx.x; // 0..63
    const float* xrow = x + (size_t)b * E;
    size_t woff = (size_t)d * E;
    float aq = 0.f, ak = 0.f, av = 0.f;
    for (int i = lane * 4; i < E; i += 64 * 4) {   // 16 iters at E=4096
        float4 x4 = *(const float4*)(xrow + i);
        float4 q4 = *(const float4*)(Wq + woff + i);
        float4 k4 = *(const float4*)(Wk + woff + i);
        float4 v4 = *(const float4*)(Wv + woff + i);
        aq += x4.x*q4.x + x4.y*q4.y + x4.z*q4.z + x4.w*q4.w;
        ak += x4.x*k4.x + x4.y*k4.y + x4.z*k4.z + x4.w*k4.w;
        av += x4.x*v4.x + x4.y*v4.y + x4.z*v4.z + x4.w*v4.w;
    }
    #pragma unroll
    for (int off = 32; off >= 1; off >>= 1) {
        aq += __shfl_xor(aq, off, 64);
        ak += __shfl_xor(ak, off, 64);
        av += __shfl_xor(av, off, 64);
    }
    if (lane == 0) {
        qkv[(size_t)b * D + d] = aq;
        qkv[((size_t)B + b) * D + d] = ak;
        qkv[((size_t)2 * B + b) * D + d] = av;
    }
}

// ---------------- K2: scores + per-chunk online-softmax partials ----------------
// grid (NC, B), block 256 (4 waves). 16 lanes per k-row -> 4 rows/wave-pass.
__global__ void score_chunk_kernel(const float* __restrict__ kv,  // [2][B][MT][D]
                                   const float* __restrict__ qkv, // [3][B][D]
                                   const int* __restrict__ next_pos,
                                   float* __restrict__ s_out,     // [B][T]
                                   float* __restrict__ m_out,     // [B][NC]
                                   float* __restrict__ l_out,     // [B][NC]
                                   float* __restrict__ acc_out,   // [B][NC][D]
                                   int B, int D, int T, int MT, int NC, float scale)
{
    int c = blockIdx.x;
    int b = blockIdx.y;
    int tid = threadIdx.x;   // 0..255
    int wave = tid >> 6;
    int lane = tid & 63;
    int l16 = lane & 15;     // position within 16-lane row group
    int g16 = lane >> 4;     // row group 0..3 within wave

    __shared__ float s_sh[CHUNK];
    __shared__ float w_sh[CHUNK];
    __shared__ float part[2][128];

    int np = next_pos[b];
    int t0 = c * CHUNK;
    const float* q    = qkv + (size_t)b * D;
    const float* knew = qkv + ((size_t)B + b) * D;
    const float* vnew = qkv + ((size_t)2 * B + b) * D;
    const float* kbase = kv + (size_t)b * MT * D;
    const float* vbase = kv + ((size_t)B + b) * MT * D;

    // q fragment: 8 floats/lane (d = l16*8 .. +8), L2-hot
    float4 qa = *(const float4*)(q + l16 * 8);
    float4 qb = *(const float4*)(q + l16 * 8 + 4);

    // scores: wave handles rows [wave*8, wave*8+8) in 2 passes of 4 rows
    #pragma unroll
    for (int p = 0; p < 2; ++p) {
        int j = wave * 8 + p * 4 + g16;
        int t = t0 + j;
        const float* krow = (t == np) ? knew : (kbase + (size_t)t * D);
        float4 ka = *(const float4*)(krow + l16 * 8);
        float4 kb = *(const float4*)(krow + l16 * 8 + 4);
        float ps = qa.x*ka.x + qa.y*ka.y + qa.z*ka.z + qa.w*ka.w
                 + qb.x*kb.x + qb.y*kb.y + qb.z*kb.z + qb.w*kb.w;
        ps += __shfl_xor(ps, 1, 64);
        ps += __shfl_xor(ps, 2, 64);
        ps += __shfl_xor(ps, 4, 64);
        ps += __shfl_xor(ps, 8, 64);
        if (l16 == 0) {
            float sv = (t < T) ? ps * scale : -1e30f;
            s_sh[j] = sv;
            if (t < T) s_out[(size_t)b * T + t] = sv;
        }
    }
    __syncthreads();

    // wave 0: chunk max, weights, weight-sum (32 scores, duplicated per half)
    if (wave == 0) {
        float sv = s_sh[lane & 31];
        float m = sv;
        #pragma unroll
        for (int off = 16; off >= 1; off >>= 1)
            m = fmaxf(m, __shfl_xor(m, off, 64));
        float w = __expf(sv - m);
        w_sh[lane & 31] = w;
        float l = w;
        #pragma unroll
        for (int off = 16; off >= 1; off >>= 1)
            l += __shfl_xor(l, off, 64);
        if (lane == 0) {
            m_out[(size_t)b * NC + c] = m;
            l_out[(size_t)b * NC + c] = l;
        }
    }
    __syncthreads();

    // v accumulation: 2 groups of 128 threads, 16 j's each
    int gg = tid >> 7;
    int d = tid & 127;
    float a = 0.f;
    #pragma unroll
    for (int jj = 0; jj < 16; ++jj) {
        int j = gg * 16 + jj;
        int t = t0 + j;
        const float* vrow = (t == np) ? vnew : (vbase + (size_t)t * D);
        a += w_sh[j] * vrow[d];
    }
    part[gg][d] = a;
    __syncthreads();
    if (tid < 128)
        acc_out[((size_t)b * NC + c) * D + tid] = part[0][tid] + part[1][tid];
}

// ---------------- K3: carry-in combine + prefix outputs ----------------
// grid (NC, B), block 256. Waves 0-1: carry-in from L2; waves 2-3: stage v
// into LDS concurrently. Then 32-step prefix runs at LDS latency.
__global__ void out_kernel(const float* __restrict__ kv,
                           const float* __restrict__ qkv,
                           const int* __restrict__ next_pos,
                           const float* __restrict__ s_in,   // [B][T]
                           const float* __restrict__ m_in,   // [B][NC]
                           const float* __restrict__ l_in,   // [B][NC]
                           const float* __restrict__ acc_in, // [B][NC][D]
                           float* __restrict__ out,          // [B][T][D]
                           int B, int D, int T, int MT, int NC)
{
    int c = blockIdx.x;
    int b = blockIdx.y;
    int tid = threadIdx.x; // 0..255

    __shared__ float vs[CHUNK * 128];  // 16 KB staged v rows
    __shared__ float w_sh[CHUNK];
    __shared__ float rl_sh[CHUNK];
    __shared__ float M_sh;

    int np = next_pos[b];
    int t0 = c * CHUNK;
    const float* mrow = m_in + (size_t)b * NC;
    const float* lrow = l_in + (size_t)b * NC;

    // phase 0: M = max over chunks cc <= c (wave 0, shuffle reduce)
    if (tid < 64) {
        float mv = (tid <= c) ? mrow[tid] : -1e30f;
        #pragma unroll
        for (int off = 32; off >= 1; off >>= 1)
            mv = fmaxf(mv, __shfl_xor(mv, off, 64));
        if (tid == 0) M_sh = mv;
    }
    __syncthreads();
    float M = M_sh;

    const float* vbase = kv + ((size_t)B + b) * MT * D;
    const float4* vnew4 = (const float4*)(qkv + ((size_t)2 * B + b) * D);
    const float4* vbase4 = (const float4*)vbase;

    float A = 0.f;
    if (tid < 128) {
        // carry-in numerator for this d (acc_in is L2-resident, ~786 KB total)
        const float* arow0 = acc_in + (size_t)b * NC * D;
        for (int cc = 0; cc < c; ++cc) {
            float e = __expf(mrow[cc] - M);
            A += e * arow0[(size_t)cc * D + tid];
        }
    } else {
        // stage v rows (coalesced float4) + this chunk's weights
        int t2 = tid - 128;
        #pragma unroll
        for (int r = 0; r < 8; ++r) {
            int i4 = t2 + r * 128;            // 0..1023 float4 slots
            int j = i4 >> 5;                  // row (32 float4 per row)
            int t = t0 + j;
            float4 vv = (t == np) ? vnew4[i4 & 31]
                                  : vbase4[(size_t)t * 32 + (i4 & 31)];
            ((float4*)vs)[i4] = vv;
        }
        if (t2 < CHUNK) {
            int t = t0 + t2;
            w_sh[t2] = (t < T) ? __expf(s_in[(size_t)b * T + t] - M) : 0.f;
        }
    }
    __syncthreads();

    // per-row reciprocal denominators (32 parallel divides)
    if (tid < CHUNK) {
        float L = 0.f;
        for (int cc = 0; cc < c; ++cc)
            L += lrow[cc] * __expf(mrow[cc] - M);
        for (int r = 0; r <= tid; ++r)
            L += w_sh[r];
        rl_sh[tid] = 1.0f / L;
    }
    __syncthreads();

    // prefix stream from LDS, coalesced stores
    if (tid < 128) {
        float* orow = out + ((size_t)b * T + t0) * (size_t)D + tid;
        #pragma unroll
        for (int j = 0; j < CHUNK; ++j) {
            int t = t0 + j;
            if (t >= T) break;
            A += w_sh[j] * vs[j * 128 + tid];
            orow[(size_t)j * D] = A * rl_sh[j];
        }
    }
}

extern "C" void kernel_launch(void* const* d_in, const int* in_sizes, int n_in,
                              void* d_out, int out_size, void* d_ws, size_t ws_size,
                              hipStream_t stream) {
    const float* x        = (const float*)d_in[0];
    const float* Wq       = (const float*)d_in[1];
    const float* Wk       = (const float*)d_in[2];
    const float* Wv       = (const float*)d_in[3];
    const float* kv       = (const float*)d_in[4];
    const int*   next_pos = (const int*)d_in[5];
    float* out = (float*)d_out;

    const int B  = in_sizes[5];                 // 32
    const int E  = in_sizes[0] / B;             // 4096
    const int D  = in_sizes[1] / E;             // 128
    const int T  = out_size / (B * D);          // 1536
    const int MT = in_sizes[4] / (2 * B * D);   // 2048
    const int NC = (T + CHUNK - 1) / CHUNK;     // 48

    float* ws   = (float*)d_ws;
    float* qkv  = ws;                            // 3*B*D
    float* s    = qkv + (size_t)3 * B * D;       // B*T
    float* m    = s + (size_t)B * T;             // B*NC
    float* l    = m + (size_t)B * NC;            // B*NC
    float* acc  = l + (size_t)B * NC;            // B*NC*D

    const float scale = 1.0f / sqrtf((float)D);

    proj_kernel<<<dim3(D, B), 64, 0, stream>>>(x, Wq, Wk, Wv, qkv, B, E, D);
    score_chunk_kernel<<<dim3(NC, B), 256, 0, stream>>>(kv, qkv, next_pos,
                                                        s, m, l, acc,
                                                        B, D, T, MT, NC, scale);
    out_kernel<<<dim3(NC, B), 256, 0, stream>>>(kv, qkv, next_pos,
                                                s, m, l, acc, out,
                                                B, D, T, MT, NC);
}

// Round 3
// 135.171 us; speedup vs baseline: 1.3187x; 1.0238x over previous
//
#include <hip/hip_runtime.h>
#include <math.h>

#define CHUNK 32   // rows per chunk; NC = T/32 = 48 for T=1536
#define MAXNC 128  // scan kernel LDS bound (supports T up to 4096)

// ---------------- K1: fused q/k/v projections ----------------
// grid (D, B), block 64. One wave computes q[d],k[d],v[d] for batch b.
__global__ void proj_kernel(const float* __restrict__ x,
                            const float* __restrict__ Wq,
                            const float* __restrict__ Wk,
                            const float* __restrict__ Wv,
                            float* __restrict__ qkv, // [3][B][D]
                            int B, int E, int D)
{
    int d = blockIdx.x;
    int b = blockIdx.y;
    int lane = threadIdx.x; // 0..63
    const float* xrow = x + (size_t)b * E;
    size_t woff = (size_t)d * E;
    float aq = 0.f, ak = 0.f, av = 0.f;
    for (int i = lane * 4; i < E; i += 64 * 4) {   // 16 iters at E=4096
        float4 x4 = *(const float4*)(xrow + i);
        float4 q4 = *(const float4*)(Wq + woff + i);
        float4 k4 = *(const float4*)(Wk + woff + i);
        float4 v4 = *(const float4*)(Wv + woff + i);
        aq += x4.x*q4.x + x4.y*q4.y + x4.z*q4.z + x4.w*q4.w;
        ak += x4.x*k4.x + x4.y*k4.y + x4.z*k4.z + x4.w*k4.w;
        av += x4.x*v4.x + x4.y*v4.y + x4.z*v4.z + x4.w*v4.w;
    }
    #pragma unroll
    for (int off = 32; off >= 1; off >>= 1) {
        aq += __shfl_xor(aq, off, 64);
        ak += __shfl_xor(ak, off, 64);
        av += __shfl_xor(av, off, 64);
    }
    if (lane == 0) {
        qkv[(size_t)b * D + d] = aq;
        qkv[((size_t)B + b) * D + d] = ak;
        qkv[((size_t)2 * B + b) * D + d] = av;
    }
}

// ---------------- K2: scores + per-chunk online-softmax partials ----------------
// grid (NC, B), block 256 (4 waves).
__global__ void score_chunk_kernel(const float* __restrict__ kv,  // [2][B][MT][D]
                                   const float* __restrict__ qkv, // [3][B][D]
                                   const int* __restrict__ next_pos,
                                   float* __restrict__ s_out,     // [B][T]
                                   float* __restrict__ m_out,     // [B][NC]
                                   float* __restrict__ l_out,     // [B][NC]
                                   float* __restrict__ acc_out,   // [B][NC][D]
                                   int B, int D, int T, int MT, int NC, float scale)
{
    int c = blockIdx.x;
    int b = blockIdx.y;
    int tid = threadIdx.x;   // 0..255
    int wave = tid >> 6;
    int lane = tid & 63;
    int l16 = lane & 15;     // position within 16-lane row group
    int g16 = lane >> 4;     // row group 0..3 within wave

    __shared__ float s_sh[CHUNK];
    __shared__ float w_sh[CHUNK];
    __shared__ float part[8][128];

    int np = next_pos[b];
    int t0 = c * CHUNK;
    const float* q    = qkv + (size_t)b * D;
    const float* knew = qkv + ((size_t)B + b) * D;
    const float* kbase = kv + (size_t)b * MT * D;
    const float4* vnew4 = (const float4*)(qkv + ((size_t)2 * B + b) * D);
    const float4* vbase4 = (const float4*)(kv + ((size_t)B + b) * MT * D);

    // q fragment: 8 floats/lane (d = l16*8 .. +8), L2-hot
    float4 qa = *(const float4*)(q + l16 * 8);
    float4 qb = *(const float4*)(q + l16 * 8 + 4);

    // scores: wave handles rows [wave*8, wave*8+8) in 2 passes of 4 rows
    #pragma unroll
    for (int p = 0; p < 2; ++p) {
        int j = wave * 8 + p * 4 + g16;
        int t = t0 + j;
        const float* krow = (t == np) ? knew : (kbase + (size_t)t * D);
        float4 ka = *(const float4*)(krow + l16 * 8);
        float4 kb = *(const float4*)(krow + l16 * 8 + 4);
        float ps = qa.x*ka.x + qa.y*ka.y + qa.z*ka.z + qa.w*ka.w
                 + qb.x*kb.x + qb.y*kb.y + qb.z*kb.z + qb.w*kb.w;
        ps += __shfl_xor(ps, 1, 64);
        ps += __shfl_xor(ps, 2, 64);
        ps += __shfl_xor(ps, 4, 64);
        ps += __shfl_xor(ps, 8, 64);
        if (l16 == 0) {
            float sv = (t < T) ? ps * scale : -1e30f;
            s_sh[j] = sv;
            if (t < T) s_out[(size_t)b * T + t] = sv;
        }
    }
    __syncthreads();

    // wave 0: chunk max, weights, weight-sum (32 scores, duplicated per half)
    if (wave == 0) {
        float sv = s_sh[lane & 31];
        float m = sv;
        #pragma unroll
        for (int off = 16; off >= 1; off >>= 1)
            m = fmaxf(m, __shfl_xor(m, off, 64));
        float w = __expf(sv - m);
        w_sh[lane & 31] = w;
        float l = w;
        #pragma unroll
        for (int off = 16; off >= 1; off >>= 1)
            l += __shfl_xor(l, off, 64);
        if (lane == 0) {
            m_out[(size_t)b * NC + c] = m;
            l_out[(size_t)b * NC + c] = l;
        }
    }
    __syncthreads();

    // v accumulation: 8 row-groups x 32 float4-columns, float4 loads
    int rg = tid >> 5;       // 0..7 (4 rows each)
    int d4 = tid & 31;       // float4 column
    float4 a4 = make_float4(0.f, 0.f, 0.f, 0.f);
    #pragma unroll
    for (int p = 0; p < 4; ++p) {
        int j = rg * 4 + p;
        int t = t0 + j;
        float4 vv = (t == np) ? vnew4[d4] : vbase4[(size_t)t * 32 + d4];
        float w = w_sh[j];
        a4.x += w * vv.x; a4.y += w * vv.y; a4.z += w * vv.z; a4.w += w * vv.w;
    }
    ((float4*)&part[rg][d4 * 4])[0] = a4;
    __syncthreads();
    if (tid < 128) {
        float s = 0.f;
        #pragma unroll
        for (int r = 0; r < 8; ++r) s += part[r][tid];
        acc_out[((size_t)b * NC + c) * D + tid] = s;
    }
}

// ---------------- K2b: cross-chunk online-softmax scan ----------------
// grid (B), block 128 (thread = d). Emits exclusive carries per chunk.
__global__ void scan_kernel(const float* __restrict__ m_in,   // [B][NC]
                            const float* __restrict__ l_in,   // [B][NC]
                            const float* __restrict__ acc_in, // [B][NC][D]
                            float* __restrict__ Mc_out,       // [B][NC] running max
                            float* __restrict__ carryL_out,   // [B][NC]
                            float* __restrict__ carryA_out,   // [B][NC][D]
                            int B, int D, int NC)
{
    int b = blockIdx.x;
    int tid = threadIdx.x; // 0..127 = d

    extern __shared__ float sh[];            // accs[NC*128] + m_l[NC] + l_l[NC]
    float* accs = sh;
    float* m_l  = sh + (size_t)NC * 128;
    float* l_l  = m_l + NC;

    // stage all chunk partials (coalesced float4)
    const float4* asrc = (const float4*)(acc_in + (size_t)b * NC * D);
    float4* adst = (float4*)accs;
    for (int i = tid; i < NC * 32; i += 128)
        adst[i] = asrc[i];
    if (tid < NC) {
        m_l[tid] = m_in[(size_t)b * NC + tid];
        l_l[tid] = l_in[(size_t)b * NC + tid];
    }
    __syncthreads();

    float M = -1e30f, A = 0.f, L = 0.f;
    float* caout = carryA_out + (size_t)b * NC * D + tid;
    for (int c = 0; c < NC; ++c) {
        float mc = m_l[c];
        float Mn = fmaxf(M, mc);
        float e_old = __expf(M - Mn);
        float Ac = A * e_old;                 // exclusive carry numerator
        caout[(size_t)c * D] = Ac;
        if (tid == 0) {
            Mc_out[(size_t)b * NC + c] = Mn;
            carryL_out[(size_t)b * NC + c] = L * e_old;
        }
        float e_c = __expf(mc - Mn);
        A = Ac + e_c * accs[c * 128 + tid];
        L = L * e_old + e_c * l_l[c];
        M = Mn;
    }
}

// ---------------- K3: per-chunk prefix outputs ----------------
// grid (NC, B), block 256. Lower 128 threads: carry + prefix; upper: stage v.
__global__ void out_kernel(const float* __restrict__ kv,
                           const float* __restrict__ qkv,
                           const int* __restrict__ next_pos,
                           const float* __restrict__ s_in,     // [B][T]
                           const float* __restrict__ Mc_in,    // [B][NC]
                           const float* __restrict__ carryL_in,// [B][NC]
                           const float* __restrict__ carryA_in,// [B][NC][D]
                           float* __restrict__ out,            // [B][T][D]
                           int B, int D, int T, int MT, int NC)
{
    int c = blockIdx.x;
    int b = blockIdx.y;
    int tid = threadIdx.x; // 0..255

    __shared__ float vs[CHUNK * 128];  // 16 KB staged v rows
    __shared__ float w_sh[CHUNK];
    __shared__ float rl_sh[CHUNK];

    int np = next_pos[b];
    int t0 = c * CHUNK;
    float M = Mc_in[(size_t)b * NC + c];

    const float4* vnew4 = (const float4*)(qkv + ((size_t)2 * B + b) * D);
    const float4* vbase4 = (const float4*)(kv + ((size_t)B + b) * MT * D);

    float A = 0.f;
    if (tid < 128) {
        A = carryA_in[((size_t)b * NC + c) * D + tid];   // one coalesced read
        if (tid < CHUNK) {
            int t = t0 + tid;
            w_sh[tid] = (t < T) ? __expf(s_in[(size_t)b * T + t] - M) : 0.f;
        }
    } else {
        // stage v rows (coalesced float4)
        int t2 = tid - 128;
        #pragma unroll
        for (int r = 0; r < 8; ++r) {
            int i4 = t2 + r * 128;            // 0..1023 float4 slots
            int j = i4 >> 5;                  // row (32 float4 per row)
            int t = t0 + j;
            float4 vv = (t == np) ? vnew4[i4 & 31]
                                  : vbase4[(size_t)t * 32 + (i4 & 31)];
            ((float4*)vs)[i4] = vv;
        }
    }
    __syncthreads();

    // per-row reciprocal denominators (32 parallel divides)
    if (tid < CHUNK) {
        float L = carryL_in[(size_t)b * NC + c];
        for (int r = 0; r <= tid; ++r)
            L += w_sh[r];
        rl_sh[tid] = 1.0f / L;
    }
    __syncthreads();

    // prefix stream from LDS, coalesced stores
    if (tid < 128) {
        float* orow = out + ((size_t)b * T + t0) * (size_t)D + tid;
        #pragma unroll
        for (int j = 0; j < CHUNK; ++j) {
            int t = t0 + j;
            if (t >= T) break;
            A += w_sh[j] * vs[j * 128 + tid];
            orow[(size_t)j * D] = A * rl_sh[j];
        }
    }
}

extern "C" void kernel_launch(void* const* d_in, const int* in_sizes, int n_in,
                              void* d_out, int out_size, void* d_ws, size_t ws_size,
                              hipStream_t stream) {
    const float* x        = (const float*)d_in[0];
    const float* Wq       = (const float*)d_in[1];
    const float* Wk       = (const float*)d_in[2];
    const float* Wv       = (const float*)d_in[3];
    const float* kv       = (const float*)d_in[4];
    const int*   next_pos = (const int*)d_in[5];
    float* out = (float*)d_out;

    const int B  = in_sizes[5];                 // 32
    const int E  = in_sizes[0] / B;             // 4096
    const int D  = in_sizes[1] / E;             // 128
    const int T  = out_size / (B * D);          // 1536
    const int MT = in_sizes[4] / (2 * B * D);   // 2048
    const int NC = (T + CHUNK - 1) / CHUNK;     // 48

    float* ws     = (float*)d_ws;
    float* qkv    = ws;                             // 3*B*D
    float* s      = qkv + (size_t)3 * B * D;        // B*T
    float* m      = s + (size_t)B * T;              // B*NC
    float* l      = m + (size_t)B * NC;             // B*NC
    float* acc    = l + (size_t)B * NC;             // B*NC*D
    float* Mc     = acc + (size_t)B * NC * D;       // B*NC
    float* carryL = Mc + (size_t)B * NC;            // B*NC
    float* carryA = carryL + (size_t)B * NC;        // B*NC*D

    const float scale = 1.0f / sqrtf((float)D);

    proj_kernel<<<dim3(D, B), 64, 0, stream>>>(x, Wq, Wk, Wv, qkv, B, E, D);
    score_chunk_kernel<<<dim3(NC, B), 256, 0, stream>>>(kv, qkv, next_pos,
                                                        s, m, l, acc,
                                                        B, D, T, MT, NC, scale);
    size_t scan_lds = ((size_t)NC * 128 + 2 * NC) * sizeof(float);
    scan_kernel<<<dim3(B), 128, scan_lds, stream>>>(m, l, acc, Mc, carryL, carryA,
                                                    B, D, NC);
    out_kernel<<<dim3(NC, B), 256, 0, stream>>>(kv, qkv, next_pos,
                                                s, Mc, carryL, carryA, out,
                                                B, D, T, MT, NC);
}